// Round 14
// baseline (104.551 us; speedup 1.0000x reference)
//
#include <hip/hip_runtime.h>
#include <cstdint>
#include <cstddef>

#define NN 50000
#define NE 800000
#define GRAPHS 512
#define NBK 782                               // ceil(50000/64) buckets of 64 nodes
#define CAP 2048                              // edge capacity per bucket (mean 1024)
#define GG1 782                               // gemm_l1 blocks in merged dispatch

typedef __attribute__((ext_vector_type(8))) short bf16x8;
typedef __attribute__((ext_vector_type(4))) float f32x4;
typedef __attribute__((ext_vector_type(2))) float f32x2;

__device__ __forceinline__ unsigned short f2bf(float f) {
  union { float f; unsigned u; } v; v.f = f;
  unsigned r = v.u + 0x7FFF + ((v.u >> 16) & 1);   // RNE
  return (unsigned short)(r >> 16);
}
__device__ __forceinline__ float bf2f(unsigned short h) {
  union { unsigned u; float f; } v; v.u = ((unsigned)h) << 16;
  return v.f;
}
__device__ __forceinline__ float4 bfq(unsigned lo, unsigned hi) {
  return make_float4(bf2f((unsigned short)(lo & 0xFFFF)),
                     bf2f((unsigned short)(lo >> 16)),
                     bf2f((unsigned short)(hi & 0xFFFF)),
                     bf2f((unsigned short)(hi >> 16)));
}

// ---------------- fp8 e4m3fn helpers (HW cvt with SW fallback) ----------------
__device__ __forceinline__ unsigned char f2fp8_sw(float f) {
  union { float f; unsigned u; } v; v.f = f;
  unsigned s = (v.u >> 24) & 0x80;
  unsigned u = v.u & 0x7fffffffu;
  if (u < 0x3c000000u) {
    float a = fabsf(f) * 512.0f;
    int mi = (int)(a + 0.5f); if (mi > 7) mi = 7;
    return (unsigned char)(s | mi);
  }
  unsigned r = u + 0x7FFFF + ((u >> 20) & 1);
  int e = (int)(r >> 23) - 127;
  unsigned m = (r >> 20) & 7;
  if (e > 8) { e = 8; m = 6; }
  return (unsigned char)(s | ((unsigned)(e + 7) << 3) | m);
}
__device__ __forceinline__ float fp82f_sw(unsigned b) {
  unsigned s = (b & 0x80) << 24;
  unsigned e = (b >> 3) & 0xF, m = b & 7;
  union { unsigned u; float f; } v;
  if (e == 0) {
    float sub = (float)m * 0.001953125f;
    return (b & 0x80) ? -sub : sub;
  }
  v.u = s | ((e + 120) << 23) | (m << 20);
  return v.f;
}
__device__ __forceinline__ void fp8pair(float a, float b,
                                        unsigned char& c0, unsigned char& c1) {
#if __has_builtin(__builtin_amdgcn_cvt_pk_fp8_f32)
  int p = __builtin_amdgcn_cvt_pk_fp8_f32(a, b, 0, false);
  c0 = (unsigned char)(p & 0xFF); c1 = (unsigned char)((p >> 8) & 0xFF);
#else
  c0 = f2fp8_sw(a); c1 = f2fp8_sw(b);
#endif
}
__device__ __forceinline__ float4 fp8x4_dec(unsigned u) {
#if __has_builtin(__builtin_amdgcn_cvt_pk_f32_fp8)
  f32x2 lo = __builtin_amdgcn_cvt_pk_f32_fp8((int)u, false);
  f32x2 hi = __builtin_amdgcn_cvt_pk_f32_fp8((int)u, true);
  return make_float4(lo[0], lo[1], hi[0], hi[1]);
#else
  return make_float4(fp82f_sw(u & 0xFF), fp82f_sw((u >> 8) & 0xFF),
                     fp82f_sw((u >> 16) & 0xFF), fp82f_sw((u >> 24) & 0xFF));
#endif
}
__device__ __forceinline__ void add16(uint4 u, float4* a) {
  float4 v0 = fp8x4_dec(u.x), v1 = fp8x4_dec(u.y);
  float4 v2 = fp8x4_dec(u.z), v3 = fp8x4_dec(u.w);
  a[0].x += v0.x; a[0].y += v0.y; a[0].z += v0.z; a[0].w += v0.w;
  a[1].x += v1.x; a[1].y += v1.y; a[1].z += v1.z; a[1].w += v1.w;
  a[2].x += v2.x; a[2].y += v2.y; a[2].z += v2.z; a[2].w += v2.w;
  a[3].x += v3.x; a[3].y += v3.y; a[3].z += v3.z; a[3].w += v3.w;
}

// ---- 16-channel gather: 4 lanes/node, 16B/lane, one 64B line per edge-row ----
__device__ __forceinline__ void gather16(
    const unsigned short* __restrict__ rootPrev,
    const unsigned char* __restrict__ hWp,
    const unsigned short* __restrict__ ssrc,
    const int* __restrict__ rs, const int* __restrict__ ren,
    int node, int c16, float4* a) {
  uint4 r0 = *(const uint4*)&rootPrev[(size_t)node * 64 + c16];
  uint4 r1 = *(const uint4*)&rootPrev[(size_t)node * 64 + c16 + 8];
  a[0] = bfq(r0.x, r0.y); a[1] = bfq(r0.z, r0.w);
  a[2] = bfq(r1.x, r1.y); a[3] = bfq(r1.z, r1.w);
  int e = rs[node];
  const int s1 = ren[node];
  for (; e + 4 <= s1; e += 4) {               // 4 x 16-line wave requests in flight
    uint4 u0 = *(const uint4*)&hWp[(size_t)ssrc[e]     * 64 + c16];
    uint4 u1 = *(const uint4*)&hWp[(size_t)ssrc[e + 1] * 64 + c16];
    uint4 u2 = *(const uint4*)&hWp[(size_t)ssrc[e + 2] * 64 + c16];
    uint4 u3 = *(const uint4*)&hWp[(size_t)ssrc[e + 3] * 64 + c16];
    add16(u0, a); add16(u1, a); add16(u2, a); add16(u3, a);
  }
  for (; e < s1; ++e) {
    uint4 u0 = *(const uint4*)&hWp[(size_t)ssrc[e] * 64 + c16];
    add16(u0, a);
  }
}

// ---- setup: zero bcnt+pooled, graph bounds, weight transpose/cast ----
__global__ __launch_bounds__(256) void setup_kernel(
    const int* __restrict__ batch, int* __restrict__ gstart,
    int* __restrict__ bcnt, float* __restrict__ pooled,
    const float* __restrict__ Wrel1, const float* __restrict__ Wroot1,
    const float* __restrict__ Wrel2, const float* __restrict__ Wroot2,
    const float* __restrict__ Wrel3, const float* __restrict__ Wroot3,
    unsigned short* __restrict__ Wt1, unsigned short* __restrict__ Wt2,
    unsigned short* __restrict__ Wt3) {
  const int tid = blockIdx.x * 256 + threadIdx.x;
  const int stride = gridDim.x * 256;
  for (int i = tid; i < NBK; i += stride) bcnt[i] = 0;
  for (int i = tid; i < GRAPHS * 64; i += stride) pooled[i] = 0.f;
  for (int g = tid; g <= GRAPHS; g += stride) {
    int lo = 0, hi = NN;                      // lower_bound(batch, g)
    while (lo < hi) {
      int mid = (lo + hi) >> 1;
      if (batch[mid] < g) lo = mid + 1; else hi = mid;
    }
    gstart[g] = lo;
  }
  for (int idx = tid; idx < 128 * 128; idx += stride) {
    int c = idx >> 7, k = idx & 127;
    Wt1[c * 128 + k] = f2bf(c < 64 ? Wrel1[k * 64 + c] : Wroot1[k * 64 + (c - 64)]);
  }
  for (int idx = tid; idx < 128 * 64; idx += stride) {
    int c = idx >> 6, k = idx & 63;
    Wt2[c * 64 + k] = f2bf(c < 64 ? Wrel2[k * 64 + c] : Wroot2[k * 64 + (c - 64)]);
    Wt3[c * 64 + k] = f2bf(c < 64 ? Wrel3[k * 64 + c] : Wroot3[k * 64 + (c - 64)]);
  }
}

// ======== merged dispatch: blocks [0,GG1) = layer-1 GEMM; rest = edge binning ======
__global__ __launch_bounds__(256) void bin_gemm1_kernel(
    const float* __restrict__ h, const unsigned short* __restrict__ Wt,
    const float* __restrict__ brel,
    unsigned char* __restrict__ hW, unsigned short* __restrict__ root,
    const int* __restrict__ src, const int* __restrict__ dst,
    int* __restrict__ bcnt, unsigned* __restrict__ ebuf) {
  __shared__ __align__(16) char smem[32768];
  const int t = threadIdx.x;

  if (blockIdx.x < GG1) {                     // ---------- gemm_l1 ----------
    constexpr int K = 128;
    unsigned short* bs = (unsigned short*)smem;            // 128*128*2 = 32KB
    constexpr int SEG = K / 8;
    const int row0 = blockIdx.x * 64;

    for (int idx = t; idx < 128 * SEG; idx += 256) {
      int c = idx / SEG, kq = idx % SEG;
      uint4 v = *(const uint4*)&Wt[c * K + kq * 8];
      int sidx = (c * K + kq * 8) ^ ((c & 7) << 3);
      *(uint4*)&bs[sidx] = v;
    }

    const int lane = t & 63, wave = t >> 6;
    const int li = lane & 15;
    const int kg = (lane >> 4) * 8;
    const int ar_node = row0 + wave * 16 + li;
    const bool valid = ar_node < NN;

    bf16x8 af[4];
    #pragma unroll
    for (int i = 0; i < 4; ++i) {
      float4 v0 = make_float4(0.f, 0.f, 0.f, 0.f), v1 = v0;
      if (valid) {
        const float* p = &h[(size_t)ar_node * K + i * 32 + kg];
        v0 = *(const float4*)p; v1 = *(const float4*)(p + 4);
      }
      union { bf16x8 b; uint4 u; } pk;
      pk.u.x = f2bf(v0.x) | ((unsigned)f2bf(v0.y) << 16);
      pk.u.y = f2bf(v0.z) | ((unsigned)f2bf(v0.w) << 16);
      pk.u.z = f2bf(v1.x) | ((unsigned)f2bf(v1.y) << 16);
      pk.u.w = f2bf(v1.z) | ((unsigned)f2bf(v1.w) << 16);
      af[i] = pk.b;
    }
    __syncthreads();

    f32x4 acc[8];
    #pragma unroll
    for (int i = 0; i < 8; ++i) acc[i] = (f32x4){0.f, 0.f, 0.f, 0.f};

    #pragma unroll
    for (int i = 0; i < 4; ++i) {
      int ka = i * 32 + kg;
      #pragma unroll
      for (int nb = 0; nb < 8; ++nb) {
        int bc = nb * 16 + li;
        bf16x8 b = *(bf16x8*)&bs[(bc * K + ka) ^ ((bc & 7) << 3)];
        acc[nb] = __builtin_amdgcn_mfma_f32_16x16x32_bf16(af[i], b, acc[nb], 0, 0, 0);
      }
    }

    const int orow = row0 + wave * 16 + (lane >> 4) * 4;
    #pragma unroll
    for (int nb = 0; nb < 4; ++nb) {          // rel half -> hW (fp8)
      unsigned char cb[4];
      fp8pair(acc[nb][0], acc[nb][1], cb[0], cb[1]);
      fp8pair(acc[nb][2], acc[nb][3], cb[2], cb[3]);
      #pragma unroll
      for (int r = 0; r < 4; ++r) {
        int node = orow + r;
        if (node < NN) hW[(size_t)node * 64 + nb * 16 + li] = cb[r];
      }
    }
    #pragma unroll
    for (int nb = 4; nb < 8; ++nb) {          // root half -> bf16 (+bias)
      float bb = brel[(nb - 4) * 16 + li];
      #pragma unroll
      for (int r = 0; r < 4; ++r) {
        int node = orow + r;
        if (node < NN) root[(size_t)node * 64 + (nb - 4) * 16 + li] = f2bf(acc[nb][r] + bb);
      }
    }
  } else {                                    // ---------- bin ----------
    int* hist = (int*)smem;
    int* base = hist + NBK;
    int* lcur = base + NBK;
    for (int b = t; b < NBK; b += 256) { hist[b] = 0; lcur[b] = 0; }
    __syncthreads();
    const int e0 = (blockIdx.x - GG1) * 4096;
    unsigned pk[16]; int bk[16];
    #pragma unroll
    for (int i = 0; i < 16; ++i) {
      int e = e0 + i * 256 + t;
      if (e < NE) {
        int s = src[e], d = dst[e];
        bk[i] = d >> 6;
        pk[i] = ((unsigned)(d & 63) << 17) | (unsigned)s;
        atomicAdd(&hist[bk[i]], 1);
      } else bk[i] = -1;
    }
    __syncthreads();
    for (int b = t; b < NBK; b += 256) {
      int c = hist[b];
      if (c) base[b] = atomicAdd(&bcnt[b], c);
    }
    __syncthreads();
    #pragma unroll
    for (int i = 0; i < 16; ++i) {
      if (bk[i] >= 0) {
        int r = atomicAdd(&lcur[bk[i]], 1);
        ebuf[(size_t)bk[i] * CAP + base[bk[i]] + r] = pk[i];
      }
    }
  }
}

// per-bucket counting sort in LDS -> per-node [rs, ren) ranges in bucketed ssrc
__global__ __launch_bounds__(256) void bucket_csr_kernel(const unsigned* __restrict__ ebuf,
                                                         const int* __restrict__ bcnt,
                                                         int* __restrict__ rs,
                                                         int* __restrict__ ren,
                                                         unsigned short* __restrict__ ssrc) {
  __shared__ int ehist[64];
  __shared__ int sd[64];
  __shared__ int ecur[64];
  const int t = threadIdx.x;
  const int b = blockIdx.x;
  const int n0 = b << 6;
  const int e0 = b * CAP;
  const int cnt = bcnt[b];
  if (t < 64) ehist[t] = 0;
  __syncthreads();
  for (int e = t; e < cnt; e += 256)
    atomicAdd(&ehist[ebuf[e0 + e] >> 17], 1);
  __syncthreads();
  if (t < 64) sd[t] = ehist[t];
  __syncthreads();
  for (int off = 1; off < 64; off <<= 1) {
    int u = (t >= off && t < 64) ? sd[t - off] : 0;
    __syncthreads();
    if (t < 64) sd[t] += u;
    __syncthreads();
  }
  if (t < 64) {
    int ex = e0 + sd[t] - ehist[t];
    ecur[t] = ex;
    rs[n0 + t] = ex;
    ren[n0 + t] = e0 + sd[t];
  }
  __syncthreads();
  for (int e = t; e < cnt; e += 256) {
    unsigned ed = ebuf[e0 + e];
    int r = atomicAdd(&ecur[ed >> 17], 1);
    ssrc[r] = (unsigned short)(ed & 0xFFFF);  // src < 50000 < 65536
  }
}

// ===== layers 2/3 fused: 64-node block; a = relu(root + G(hWp)); GEMM =====
__global__ __launch_bounds__(256) void agg_gemm_kernel(
    const unsigned short* __restrict__ rootPrev,  // [NN][64] bf16 (incl. prev bias)
    const unsigned char* __restrict__ hWp,        // [NN][64] fp8
    const int* __restrict__ rs, const int* __restrict__ ren,
    const unsigned short* __restrict__ ssrc,
    const unsigned short* __restrict__ Wt,        // [128][64] bf16
    const float* __restrict__ brel,
    unsigned char* __restrict__ hW,               // out fp8
    unsigned short* __restrict__ rootOut) {       // out bf16 (+bias)
  __shared__ __align__(16) unsigned short as[64 * 64];    // 8KB
  __shared__ __align__(16) unsigned short bs[128 * 64];   // 16KB
  const int t = threadIdx.x;
  const int n0 = blockIdx.x * 64;

  // stage B (swizzled) — issues early, overlaps gather latency
  #pragma unroll
  for (int i = 0; i < 4; ++i) {
    int idx = t + i * 256;
    int c = idx >> 3, kq = idx & 7;
    uint4 v = *(const uint4*)&Wt[c * 64 + kq * 8];
    int sidx = (c * 64 + kq * 8) ^ ((c & 7) << 3);
    *(uint4*)&bs[sidx] = v;
  }

  // gather: 4 lanes per node, 16 channels each
  const int r = t >> 2, c16 = (t & 3) * 16;
  const int node = n0 + r;
  float4 a[4];
  if (node < NN) {
    gather16(rootPrev, hWp, ssrc, rs, ren, node, c16, a);
  } else {
    a[0] = a[1] = a[2] = a[3] = make_float4(0.f, 0.f, 0.f, 0.f);
  }
  uint4 p0, p1;
  p0.x = f2bf(fmaxf(a[0].x, 0.f)) | ((unsigned)f2bf(fmaxf(a[0].y, 0.f)) << 16);
  p0.y = f2bf(fmaxf(a[0].z, 0.f)) | ((unsigned)f2bf(fmaxf(a[0].w, 0.f)) << 16);
  p0.z = f2bf(fmaxf(a[1].x, 0.f)) | ((unsigned)f2bf(fmaxf(a[1].y, 0.f)) << 16);
  p0.w = f2bf(fmaxf(a[1].z, 0.f)) | ((unsigned)f2bf(fmaxf(a[1].w, 0.f)) << 16);
  p1.x = f2bf(fmaxf(a[2].x, 0.f)) | ((unsigned)f2bf(fmaxf(a[2].y, 0.f)) << 16);
  p1.y = f2bf(fmaxf(a[2].z, 0.f)) | ((unsigned)f2bf(fmaxf(a[2].w, 0.f)) << 16);
  p1.z = f2bf(fmaxf(a[3].x, 0.f)) | ((unsigned)f2bf(fmaxf(a[3].y, 0.f)) << 16);
  p1.w = f2bf(fmaxf(a[3].z, 0.f)) | ((unsigned)f2bf(fmaxf(a[3].w, 0.f)) << 16);
  *(uint4*)&as[(r * 64 + c16) ^ ((r & 7) << 3)] = p0;
  *(uint4*)&as[(r * 64 + c16 + 8) ^ ((r & 7) << 3)] = p1;
  __syncthreads();

  // MFMA: wave w owns rows [w*16, w*16+16) x all 128 cols (round-8 verified shape)
  const int lane = t & 63, wave = t >> 6;
  const int li = lane & 15, kg = (lane >> 4) * 8;
  const int ar = wave * 16 + li;
  f32x4 acc[8];
  #pragma unroll
  for (int i = 0; i < 8; ++i) acc[i] = (f32x4){0.f, 0.f, 0.f, 0.f};

  #pragma unroll
  for (int ks = 0; ks < 2; ++ks) {
    int ka = ks * 32 + kg;
    bf16x8 av = *(bf16x8*)&as[(ar * 64 + ka) ^ ((ar & 7) << 3)];
    #pragma unroll
    for (int nb = 0; nb < 8; ++nb) {
      int bc = nb * 16 + li;
      bf16x8 bv = *(bf16x8*)&bs[(bc * 64 + ka) ^ ((bc & 7) << 3)];
      acc[nb] = __builtin_amdgcn_mfma_f32_16x16x32_bf16(av, bv, acc[nb], 0, 0, 0);
    }
  }

  const int orow = n0 + wave * 16 + (lane >> 4) * 4;
  #pragma unroll
  for (int nb = 0; nb < 4; ++nb) {            // rel half -> hW (fp8)
    unsigned char cb[4];
    fp8pair(acc[nb][0], acc[nb][1], cb[0], cb[1]);
    fp8pair(acc[nb][2], acc[nb][3], cb[2], cb[3]);
    #pragma unroll
    for (int rr = 0; rr < 4; ++rr) {
      int nd = orow + rr;
      if (nd < NN) hW[(size_t)nd * 64 + nb * 16 + li] = cb[rr];
    }
  }
  #pragma unroll
  for (int nb = 4; nb < 8; ++nb) {            // root half -> bf16 (+bias)
    float bb = brel[(nb - 4) * 16 + li];
    #pragma unroll
    for (int rr = 0; rr < 4; ++rr) {
      int nd = orow + rr;
      if (nd < NN) rootOut[(size_t)nd * 64 + (nb - 4) * 16 + li] = f2bf(acc[nb][rr] + bb);
    }
  }
}

// ===== final: 64-node block gather + relu + segmented pooled atomics =====
__global__ __launch_bounds__(256) void agg_pool_kernel(
    const unsigned short* __restrict__ rootPrev,
    const unsigned char* __restrict__ hWp,
    const int* __restrict__ rs, const int* __restrict__ ren,
    const unsigned short* __restrict__ ssrc,
    const int* __restrict__ batch,
    float* __restrict__ pooled) {
  __shared__ float h3s[64 * 64];              // 16KB
  __shared__ int batch_s[64];
  const int t = threadIdx.x;
  const int n0 = blockIdx.x * 64;
  if (t < 64) {
    int nd = n0 + t;
    batch_s[t] = batch[nd < NN ? nd : (NN - 1)];
  }

  const int r = t >> 2, c16 = (t & 3) * 16;
  const int node = n0 + r;
  float4 a[4];
  if (node < NN) {
    gather16(rootPrev, hWp, ssrc, rs, ren, node, c16, a);
    a[0].x = fmaxf(a[0].x, 0.f); a[0].y = fmaxf(a[0].y, 0.f);
    a[0].z = fmaxf(a[0].z, 0.f); a[0].w = fmaxf(a[0].w, 0.f);
    a[1].x = fmaxf(a[1].x, 0.f); a[1].y = fmaxf(a[1].y, 0.f);
    a[1].z = fmaxf(a[1].z, 0.f); a[1].w = fmaxf(a[1].w, 0.f);
    a[2].x = fmaxf(a[2].x, 0.f); a[2].y = fmaxf(a[2].y, 0.f);
    a[2].z = fmaxf(a[2].z, 0.f); a[2].w = fmaxf(a[2].w, 0.f);
    a[3].x = fmaxf(a[3].x, 0.f); a[3].y = fmaxf(a[3].y, 0.f);
    a[3].z = fmaxf(a[3].z, 0.f); a[3].w = fmaxf(a[3].w, 0.f);
  } else {
    a[0] = a[1] = a[2] = a[3] = make_float4(0.f, 0.f, 0.f, 0.f);
  }
  *(float4*)&h3s[r * 64 + c16]      = a[0];
  *(float4*)&h3s[r * 64 + c16 + 4]  = a[1];
  *(float4*)&h3s[r * 64 + c16 + 8]  = a[2];
  *(float4*)&h3s[r * 64 + c16 + 12] = a[3];
  __syncthreads();

  if (t < 64) {                               // run-accumulate by graph, then atomics
    int cur = batch_s[0]; float acc = 0.f;
    for (int rr = 0; rr < 64; ++rr) {
      int g = batch_s[rr];
      if (g != cur) {
        unsafeAtomicAdd(&pooled[cur * 64 + t], acc);
        acc = 0.f; cur = g;
      }
      acc += h3s[rr * 64 + t];
    }
    unsafeAtomicAdd(&pooled[cur * 64 + t], acc);
  }
}

// ------- MLP head: one 64-thread block per graph -------
__global__ __launch_bounds__(64) void head_kernel(
    const float* __restrict__ pooled, const int* __restrict__ gstart,
    const float* __restrict__ Wfc1, const float* __restrict__ bfc1,
    const float* __restrict__ Wfc2, const float* __restrict__ bfc2,
    float* __restrict__ out) {
  __shared__ float m[64];
  __shared__ float h1[32];
  const int g = blockIdx.x, l = threadIdx.x;
  float c = fmaxf((float)(gstart[g + 1] - gstart[g]), 1.0f);
  m[l] = pooled[g * 64 + l] / c;
  __syncthreads();
  if (l < 32) {
    float a = bfc1[l];
    #pragma unroll
    for (int k = 0; k < 64; ++k) a += m[k] * Wfc1[k * 32 + l];
    h1[l] = fmaxf(a, 0.f);
  }
  __syncthreads();
  if (l == 0) {
    float o = bfc2[0];
    #pragma unroll
    for (int j = 0; j < 32; ++j) o += h1[j] * Wfc2[j];
    out[g] = o;
  }
}

extern "C" void kernel_launch(void* const* d_in, const int* in_sizes, int n_in,
                              void* d_out, int out_size, void* d_ws, size_t ws_size,
                              hipStream_t stream) {
  const float* x      = (const float*)d_in[0];
  const int*   ei     = (const int*)d_in[1];
  const int*   batch  = (const int*)d_in[2];
  const float* Wrel1  = (const float*)d_in[3];
  const float* brel1  = (const float*)d_in[4];
  const float* Wroot1 = (const float*)d_in[5];
  const float* Wrel2  = (const float*)d_in[6];
  const float* brel2  = (const float*)d_in[7];
  const float* Wroot2 = (const float*)d_in[8];
  const float* Wrel3  = (const float*)d_in[9];
  const float* brel3  = (const float*)d_in[10];
  const float* Wroot3 = (const float*)d_in[11];
  const float* Wfc1   = (const float*)d_in[12];
  const float* bfc1   = (const float*)d_in[13];
  const float* Wfc2   = (const float*)d_in[14];
  const float* bfc2   = (const float*)d_in[15];
  const int* src = ei;
  const int* dst = ei + NE;

  char* w = (char*)d_ws;
  auto alloc = [&](size_t bytes) -> char* {
    char* p = w; w += (bytes + 255) & ~(size_t)255; return p;
  };
  unsigned char*  hWa   = (unsigned char*)alloc((size_t)NN * 64);       // fp8
  unsigned char*  hWb   = (unsigned char*)alloc((size_t)NN * 64);       // fp8
  unsigned short* rootA = (unsigned short*)alloc((size_t)NN * 64 * 2);  // bf16
  unsigned short* rootB = (unsigned short*)alloc((size_t)NN * 64 * 2);  // bf16
  int*   rs     = (int*)alloc((size_t)NBK * 64 * 4);
  int*   ren    = (int*)alloc((size_t)NBK * 64 * 4);
  unsigned short* ssrc = (unsigned short*)alloc((size_t)NBK * CAP * 2);
  int*   gstart = (int*)alloc((size_t)(GRAPHS + 1) * 4);
  int*   bcnt   = (int*)alloc((size_t)NBK * 4);
  float* pooled = (float*)alloc((size_t)GRAPHS * 64 * 4);
  unsigned* ebuf = (unsigned*)alloc((size_t)NBK * CAP * 4);
  unsigned short* Wt1 = (unsigned short*)alloc((size_t)128 * 128 * 2);
  unsigned short* Wt2 = (unsigned short*)alloc((size_t)128 * 64 * 2);
  unsigned short* Wt3 = (unsigned short*)alloc((size_t)128 * 64 * 2);

  setup_kernel<<<64, 256, 0, stream>>>(batch, gstart, bcnt, pooled,
                                       Wrel1, Wroot1, Wrel2, Wroot2, Wrel3, Wroot3,
                                       Wt1, Wt2, Wt3);
  // merged: gemm_l1 (blocks 0..781) + bin (blocks 782..977)
  bin_gemm1_kernel<<<GG1 + (NE + 4095) / 4096, 256, 0, stream>>>(
      x, Wt1, brel1, hWa, rootA, src, dst, bcnt, ebuf);
  bucket_csr_kernel<<<NBK, 256, 0, stream>>>(ebuf, bcnt, rs, ren, ssrc);

  // layer 2: a2 = relu(rootA + G(hWa)); hWb = a2@Wrel2, rootB = a2@Wroot2 + b2
  agg_gemm_kernel<<<NBK, 256, 0, stream>>>(rootA, hWa, rs, ren, ssrc,
                                           Wt2, brel2, hWb, rootB);
  // layer 3: a3 = relu(rootB + G(hWb)); hWa = a3@Wrel3, rootA = a3@Wroot3 + b3
  agg_gemm_kernel<<<NBK, 256, 0, stream>>>(rootB, hWb, rs, ren, ssrc,
                                           Wt3, brel3, hWa, rootA);
  // h3 = relu(rootA + G(hWa)) -> pooled (atomics); h3 never hits memory
  agg_pool_kernel<<<NBK, 256, 0, stream>>>(rootA, hWa, rs, ren, ssrc,
                                           batch, pooled);
  head_kernel<<<GRAPHS, 64, 0, stream>>>(pooled, gstart, Wfc1, bfc1, Wfc2, bfc2,
                                         (float*)d_out);
}

// Round 15
// 89.307 us; speedup vs baseline: 1.1707x; 1.1707x over previous
//
#include <hip/hip_runtime.h>
#include <cstdint>
#include <cstddef>

#define NN 50000
#define NE 800000
#define GRAPHS 512
#define NBK 782                               // ceil(50000/64) buckets of 64 nodes
#define CAP 2048                              // edge capacity per bucket (mean 1024)
#define GG1 782                               // gemm_l1 blocks in merged dispatch

typedef __attribute__((ext_vector_type(8))) short bf16x8;
typedef __attribute__((ext_vector_type(4))) float f32x4;
typedef __attribute__((ext_vector_type(2))) float f32x2;

__device__ __forceinline__ unsigned short f2bf(float f) {
  union { float f; unsigned u; } v; v.f = f;
  unsigned r = v.u + 0x7FFF + ((v.u >> 16) & 1);   // RNE
  return (unsigned short)(r >> 16);
}
__device__ __forceinline__ float bf2f(unsigned short h) {
  union { unsigned u; float f; } v; v.u = ((unsigned)h) << 16;
  return v.f;
}

// ---------------- fp8 e4m3fn helpers (HW cvt with SW fallback) ----------------
__device__ __forceinline__ unsigned char f2fp8_sw(float f) {
  union { float f; unsigned u; } v; v.f = f;
  unsigned s = (v.u >> 24) & 0x80;
  unsigned u = v.u & 0x7fffffffu;
  if (u < 0x3c000000u) {
    float a = fabsf(f) * 512.0f;
    int mi = (int)(a + 0.5f); if (mi > 7) mi = 7;
    return (unsigned char)(s | mi);
  }
  unsigned r = u + 0x7FFFF + ((u >> 20) & 1);
  int e = (int)(r >> 23) - 127;
  unsigned m = (r >> 20) & 7;
  if (e > 8) { e = 8; m = 6; }
  return (unsigned char)(s | ((unsigned)(e + 7) << 3) | m);
}
__device__ __forceinline__ float fp82f_sw(unsigned b) {
  unsigned s = (b & 0x80) << 24;
  unsigned e = (b >> 3) & 0xF, m = b & 7;
  union { unsigned u; float f; } v;
  if (e == 0) {
    float sub = (float)m * 0.001953125f;
    return (b & 0x80) ? -sub : sub;
  }
  v.u = s | ((e + 120) << 23) | (m << 20);
  return v.f;
}
__device__ __forceinline__ void fp8pair(float a, float b,
                                        unsigned char& c0, unsigned char& c1) {
#if __has_builtin(__builtin_amdgcn_cvt_pk_fp8_f32)
  int p = __builtin_amdgcn_cvt_pk_fp8_f32(a, b, 0, false);
  c0 = (unsigned char)(p & 0xFF); c1 = (unsigned char)((p >> 8) & 0xFF);
#else
  c0 = f2fp8_sw(a); c1 = f2fp8_sw(b);
#endif
}
__device__ __forceinline__ float4 fp8x4_dec(unsigned u) {
#if __has_builtin(__builtin_amdgcn_cvt_pk_f32_fp8)
  f32x2 lo = __builtin_amdgcn_cvt_pk_f32_fp8((int)u, false);
  f32x2 hi = __builtin_amdgcn_cvt_pk_f32_fp8((int)u, true);
  return make_float4(lo[0], lo[1], hi[0], hi[1]);
#else
  return make_float4(fp82f_sw(u & 0xFF), fp82f_sw((u >> 8) & 0xFF),
                     fp82f_sw((u >> 16) & 0xFF), fp82f_sw((u >> 24) & 0xFF));
#endif
}

// ---- setup: zero bcnt+pooled, graph bounds, weight transpose/cast ----
__global__ __launch_bounds__(256) void setup_kernel(
    const int* __restrict__ batch, int* __restrict__ gstart,
    int* __restrict__ bcnt, float* __restrict__ pooled,
    const float* __restrict__ Wrel1, const float* __restrict__ Wroot1,
    const float* __restrict__ Wrel2, const float* __restrict__ Wroot2,
    const float* __restrict__ Wrel3, const float* __restrict__ Wroot3,
    unsigned short* __restrict__ Wt1, unsigned short* __restrict__ Wt2,
    unsigned short* __restrict__ Wt3) {
  const int tid = blockIdx.x * 256 + threadIdx.x;
  const int stride = gridDim.x * 256;
  for (int i = tid; i < NBK; i += stride) bcnt[i] = 0;
  for (int i = tid; i < GRAPHS * 64; i += stride) pooled[i] = 0.f;
  for (int g = tid; g <= GRAPHS; g += stride) {
    int lo = 0, hi = NN;                      // lower_bound(batch, g)
    while (lo < hi) {
      int mid = (lo + hi) >> 1;
      if (batch[mid] < g) lo = mid + 1; else hi = mid;
    }
    gstart[g] = lo;
  }
  for (int idx = tid; idx < 128 * 128; idx += stride) {
    int c = idx >> 7, k = idx & 127;
    Wt1[c * 128 + k] = f2bf(c < 64 ? Wrel1[k * 64 + c] : Wroot1[k * 64 + (c - 64)]);
  }
  for (int idx = tid; idx < 128 * 64; idx += stride) {
    int c = idx >> 6, k = idx & 63;
    Wt2[c * 64 + k] = f2bf(c < 64 ? Wrel2[k * 64 + c] : Wroot2[k * 64 + (c - 64)]);
    Wt3[c * 64 + k] = f2bf(c < 64 ? Wrel3[k * 64 + c] : Wroot3[k * 64 + (c - 64)]);
  }
}

// ======== merged dispatch: blocks [0,GG1) = layer-1 GEMM; rest = edge binning ======
// gemm: A streamed to registers (no LDS A-tile) -> 32KB LDS -> 5 blocks/CU.
__global__ __launch_bounds__(256) void bin_gemm1_kernel(
    const float* __restrict__ h, const unsigned short* __restrict__ Wt,
    const float* __restrict__ brel,
    unsigned char* __restrict__ hW, unsigned short* __restrict__ root,
    const int* __restrict__ src, const int* __restrict__ dst,
    int* __restrict__ bcnt, unsigned* __restrict__ ebuf) {
  __shared__ __align__(16) char smem[32768];
  const int t = threadIdx.x;

  if (blockIdx.x < GG1) {                     // ---------- gemm_l1 ----------
    constexpr int K = 128;
    unsigned short* bs = (unsigned short*)smem;            // 128*128*2 = 32KB
    constexpr int SEG = K / 8;
    const int row0 = blockIdx.x * 64;

    for (int idx = t; idx < 128 * SEG; idx += 256) {
      int c = idx / SEG, kq = idx % SEG;
      uint4 v = *(const uint4*)&Wt[c * K + kq * 8];
      int sidx = (c * K + kq * 8) ^ ((c & 7) << 3);
      *(uint4*)&bs[sidx] = v;
    }

    const int lane = t & 63, wave = t >> 6;
    const int li = lane & 15;
    const int kg = (lane >> 4) * 8;
    const int ar_node = row0 + wave * 16 + li;
    const bool valid = ar_node < NN;

    // A-fragments straight from global to registers (4 k-steps x bf16x8)
    bf16x8 af[4];
    #pragma unroll
    for (int i = 0; i < 4; ++i) {
      float4 v0 = make_float4(0.f, 0.f, 0.f, 0.f), v1 = v0;
      if (valid) {
        const float* p = &h[(size_t)ar_node * K + i * 32 + kg];
        v0 = *(const float4*)p; v1 = *(const float4*)(p + 4);
      }
      union { bf16x8 b; uint4 u; } pk;
      pk.u.x = f2bf(v0.x) | ((unsigned)f2bf(v0.y) << 16);
      pk.u.y = f2bf(v0.z) | ((unsigned)f2bf(v0.w) << 16);
      pk.u.z = f2bf(v1.x) | ((unsigned)f2bf(v1.y) << 16);
      pk.u.w = f2bf(v1.z) | ((unsigned)f2bf(v1.w) << 16);
      af[i] = pk.b;
    }
    __syncthreads();

    f32x4 acc[8];
    #pragma unroll
    for (int i = 0; i < 8; ++i) acc[i] = (f32x4){0.f, 0.f, 0.f, 0.f};

    #pragma unroll
    for (int i = 0; i < 4; ++i) {
      int ka = i * 32 + kg;
      #pragma unroll
      for (int nb = 0; nb < 8; ++nb) {
        int bc = nb * 16 + li;
        bf16x8 b = *(bf16x8*)&bs[(bc * K + ka) ^ ((bc & 7) << 3)];
        acc[nb] = __builtin_amdgcn_mfma_f32_16x16x32_bf16(af[i], b, acc[nb], 0, 0, 0);
      }
    }

    const int orow = row0 + wave * 16 + (lane >> 4) * 4;
    #pragma unroll
    for (int nb = 0; nb < 4; ++nb) {          // rel half -> hW (fp8)
      unsigned char cb[4];
      fp8pair(acc[nb][0], acc[nb][1], cb[0], cb[1]);
      fp8pair(acc[nb][2], acc[nb][3], cb[2], cb[3]);
      #pragma unroll
      for (int r = 0; r < 4; ++r) {
        int node = orow + r;
        if (node < NN) hW[(size_t)node * 64 + nb * 16 + li] = cb[r];
      }
    }
    #pragma unroll
    for (int nb = 4; nb < 8; ++nb) {          // root half -> bf16 (+bias)
      float bb = brel[(nb - 4) * 16 + li];
      #pragma unroll
      for (int r = 0; r < 4; ++r) {
        int node = orow + r;
        if (node < NN) root[(size_t)node * 64 + (nb - 4) * 16 + li] = f2bf(acc[nb][r] + bb);
      }
    }
  } else {                                    // ---------- bin ----------
    int* hist = (int*)smem;
    int* base = hist + NBK;
    int* lcur = base + NBK;
    for (int b = t; b < NBK; b += 256) { hist[b] = 0; lcur[b] = 0; }
    __syncthreads();
    const int e0 = (blockIdx.x - GG1) * 4096;
    unsigned pk[16]; int bk[16];
    #pragma unroll
    for (int i = 0; i < 16; ++i) {
      int e = e0 + i * 256 + t;
      if (e < NE) {
        int s = src[e], d = dst[e];
        bk[i] = d >> 6;
        pk[i] = ((unsigned)(d & 63) << 17) | (unsigned)s;
        atomicAdd(&hist[bk[i]], 1);
      } else bk[i] = -1;
    }
    __syncthreads();
    for (int b = t; b < NBK; b += 256) {
      int c = hist[b];
      if (c) base[b] = atomicAdd(&bcnt[b], c);
    }
    __syncthreads();
    #pragma unroll
    for (int i = 0; i < 16; ++i) {
      if (bk[i] >= 0) {
        int r = atomicAdd(&lcur[bk[i]], 1);
        ebuf[(size_t)bk[i] * CAP + base[bk[i]] + r] = pk[i];
      }
    }
  }
}

// per-bucket counting sort in LDS -> per-node [rs, ren) ranges in bucketed ssrc
__global__ __launch_bounds__(256) void bucket_csr_kernel(const unsigned* __restrict__ ebuf,
                                                         const int* __restrict__ bcnt,
                                                         int* __restrict__ rs,
                                                         int* __restrict__ ren,
                                                         unsigned short* __restrict__ ssrc) {
  __shared__ int ehist[64];
  __shared__ int sd[64];
  __shared__ int ecur[64];
  const int t = threadIdx.x;
  const int b = blockIdx.x;
  const int n0 = b << 6;
  const int e0 = b * CAP;
  const int cnt = bcnt[b];
  if (t < 64) ehist[t] = 0;
  __syncthreads();
  for (int e = t; e < cnt; e += 256)
    atomicAdd(&ehist[ebuf[e0 + e] >> 17], 1);
  __syncthreads();
  if (t < 64) sd[t] = ehist[t];
  __syncthreads();
  for (int off = 1; off < 64; off <<= 1) {
    int u = (t >= off && t < 64) ? sd[t - off] : 0;
    __syncthreads();
    if (t < 64) sd[t] += u;
    __syncthreads();
  }
  if (t < 64) {
    int ex = e0 + sd[t] - ehist[t];
    ecur[t] = ex;
    rs[n0 + t] = ex;
    ren[n0 + t] = e0 + sd[t];
  }
  __syncthreads();
  for (int e = t; e < cnt; e += 256) {
    unsigned ed = ebuf[e0 + e];
    int r = atomicAdd(&ecur[ed >> 17], 1);
    ssrc[r] = (unsigned short)(ed & 0xFFFF);  // src < 50000 < 65536
  }
}

// ---- shared gather body: a = root + sum(fp8 rows), 8 loads in flight ----
__device__ __forceinline__ float4 gather_node(
    const unsigned short* __restrict__ rootPrev,
    const unsigned char* __restrict__ hWp,
    const unsigned short* __restrict__ ssrc,
    int node, int c4, int s0, int s1) {
  ushort4 rt = *(const ushort4*)&rootPrev[(size_t)node * 64 + c4];
  float4 a0 = make_float4(bf2f(rt.x), bf2f(rt.y), bf2f(rt.z), bf2f(rt.w));
  float4 a1 = make_float4(0.f, 0.f, 0.f, 0.f);
  float4 a2 = make_float4(0.f, 0.f, 0.f, 0.f);
  float4 a3 = make_float4(0.f, 0.f, 0.f, 0.f);
  int e = s0;
  for (; e + 8 <= s1; e += 8) {               // 8 independent line requests
    unsigned u0 = *(const unsigned*)&hWp[(size_t)ssrc[e]     * 64 + c4];
    unsigned u1 = *(const unsigned*)&hWp[(size_t)ssrc[e + 1] * 64 + c4];
    unsigned u2 = *(const unsigned*)&hWp[(size_t)ssrc[e + 2] * 64 + c4];
    unsigned u3 = *(const unsigned*)&hWp[(size_t)ssrc[e + 3] * 64 + c4];
    unsigned u4 = *(const unsigned*)&hWp[(size_t)ssrc[e + 4] * 64 + c4];
    unsigned u5 = *(const unsigned*)&hWp[(size_t)ssrc[e + 5] * 64 + c4];
    unsigned u6 = *(const unsigned*)&hWp[(size_t)ssrc[e + 6] * 64 + c4];
    unsigned u7 = *(const unsigned*)&hWp[(size_t)ssrc[e + 7] * 64 + c4];
    float4 v0 = fp8x4_dec(u0), v1 = fp8x4_dec(u1);
    float4 v2 = fp8x4_dec(u2), v3 = fp8x4_dec(u3);
    float4 v4 = fp8x4_dec(u4), v5 = fp8x4_dec(u5);
    float4 v6 = fp8x4_dec(u6), v7 = fp8x4_dec(u7);
    a0.x += v0.x + v4.x; a0.y += v0.y + v4.y; a0.z += v0.z + v4.z; a0.w += v0.w + v4.w;
    a1.x += v1.x + v5.x; a1.y += v1.y + v5.y; a1.z += v1.z + v5.z; a1.w += v1.w + v5.w;
    a2.x += v2.x + v6.x; a2.y += v2.y + v6.y; a2.z += v2.z + v6.z; a2.w += v2.w + v6.w;
    a3.x += v3.x + v7.x; a3.y += v3.y + v7.y; a3.z += v3.z + v7.z; a3.w += v3.w + v7.w;
  }
  if (e + 4 <= s1) {
    unsigned u0 = *(const unsigned*)&hWp[(size_t)ssrc[e]     * 64 + c4];
    unsigned u1 = *(const unsigned*)&hWp[(size_t)ssrc[e + 1] * 64 + c4];
    unsigned u2 = *(const unsigned*)&hWp[(size_t)ssrc[e + 2] * 64 + c4];
    unsigned u3 = *(const unsigned*)&hWp[(size_t)ssrc[e + 3] * 64 + c4];
    float4 v0 = fp8x4_dec(u0), v1 = fp8x4_dec(u1);
    float4 v2 = fp8x4_dec(u2), v3 = fp8x4_dec(u3);
    a0.x += v0.x; a0.y += v0.y; a0.z += v0.z; a0.w += v0.w;
    a1.x += v1.x; a1.y += v1.y; a1.z += v1.z; a1.w += v1.w;
    a2.x += v2.x; a2.y += v2.y; a2.z += v2.z; a2.w += v2.w;
    a3.x += v3.x; a3.y += v3.y; a3.z += v3.z; a3.w += v3.w;
    e += 4;
  }
  for (; e < s1; ++e) {
    unsigned uA = *(const unsigned*)&hWp[(size_t)ssrc[e] * 64 + c4];
    float4 vA = fp8x4_dec(uA);
    a0.x += vA.x; a0.y += vA.y; a0.z += vA.z; a0.w += vA.w;
  }
  a0.x += a1.x + a2.x + a3.x; a0.y += a1.y + a2.y + a3.y;
  a0.z += a1.z + a2.z + a3.z; a0.w += a1.w + a2.w + a3.w;
  return a0;
}

// ===== layers 2/3 fused: a = relu(root + G(hWp)); [hW | root'] = a @ [Wrel|Wroot] ====
__global__ __launch_bounds__(256) void agg_gemm_kernel(
    const unsigned short* __restrict__ rootPrev,  // [NN][64] bf16 (incl. prev bias)
    const unsigned char* __restrict__ hWp,        // [NN][64] fp8
    const int* __restrict__ rs, const int* __restrict__ ren,
    const unsigned short* __restrict__ ssrc,
    const unsigned short* __restrict__ Wt,        // [128][64] bf16
    const float* __restrict__ brel,
    unsigned char* __restrict__ hW,               // out fp8
    unsigned short* __restrict__ rootOut) {       // out bf16 (+bias)
  __shared__ __align__(16) unsigned short as[16 * 64];    // 2KB
  __shared__ __align__(16) unsigned short bs[128 * 64];   // 16KB
  const int t = threadIdx.x;
  const int n0 = blockIdx.x * 16;

  // stage B (swizzled) — issues early, overlaps gather latency
  #pragma unroll
  for (int i = 0; i < 4; ++i) {
    int idx = t + i * 256;
    int c = idx >> 3, kq = idx & 7;
    uint4 v = *(const uint4*)&Wt[c * 64 + kq * 8];
    int sidx = (c * 64 + kq * 8) ^ ((c & 7) << 3);
    *(uint4*)&bs[sidx] = v;
  }

  // gather: 16 lanes per node
  const int r = t >> 4, l16 = t & 15, c4 = l16 * 4;
  const int node = n0 + r;
  float4 a0 = gather_node(rootPrev, hWp, ssrc, node, c4, rs[node], ren[node]);
  a0.x = fmaxf(a0.x, 0.f); a0.y = fmaxf(a0.y, 0.f);
  a0.z = fmaxf(a0.z, 0.f); a0.w = fmaxf(a0.w, 0.f);
  uint2 p;
  p.x = f2bf(a0.x) | ((unsigned)f2bf(a0.y) << 16);
  p.y = f2bf(a0.z) | ((unsigned)f2bf(a0.w) << 16);
  *(uint2*)&as[(r * 64 + c4) ^ ((r & 7) << 3)] = p;
  __syncthreads();

  // MFMA: wave w covers cols [w*32, w*32+32); rows = the block's 16 nodes
  const int lane = t & 63, wave = t >> 6;
  const int li = lane & 15, kg = (lane >> 4) * 8;
  f32x4 acc[2];
  acc[0] = (f32x4){0.f, 0.f, 0.f, 0.f};
  acc[1] = (f32x4){0.f, 0.f, 0.f, 0.f};
  #pragma unroll
  for (int ks = 0; ks < 2; ++ks) {
    int ka = ks * 32 + kg;
    bf16x8 a = *(bf16x8*)&as[(li * 64 + ka) ^ ((li & 7) << 3)];
    #pragma unroll
    for (int nb = 0; nb < 2; ++nb) {
      int bc = wave * 32 + nb * 16 + li;
      bf16x8 b = *(bf16x8*)&bs[(bc * 64 + ka) ^ ((bc & 7) << 3)];
      acc[nb] = __builtin_amdgcn_mfma_f32_16x16x32_bf16(a, b, acc[nb], 0, 0, 0);
    }
  }

  const int orow = n0 + (lane >> 4) * 4;
  if (wave < 2) {                             // cols 0..63 = rel -> hW (fp8)
    #pragma unroll
    for (int nb = 0; nb < 2; ++nb) {
      int col = wave * 32 + nb * 16 + li;
      unsigned char cb[4];
      fp8pair(acc[nb][0], acc[nb][1], cb[0], cb[1]);
      fp8pair(acc[nb][2], acc[nb][3], cb[2], cb[3]);
      #pragma unroll
      for (int rr = 0; rr < 4; ++rr)
        hW[(size_t)(orow + rr) * 64 + col] = cb[rr];
    }
  } else {                                    // cols 64..127 = root -> bf16 (+bias)
    #pragma unroll
    for (int nb = 0; nb < 2; ++nb) {
      int col = (wave - 2) * 32 + nb * 16 + li;
      float bb = brel[col];
      #pragma unroll
      for (int rr = 0; rr < 4; ++rr)
        rootOut[(size_t)(orow + rr) * 64 + col] = f2bf(acc[nb][rr] + bb);
    }
  }
}

// ===== final: gather + relu + per-block segmented pooled atomics (h3 on-chip) =====
__global__ __launch_bounds__(256) void agg_pool_kernel(
    const unsigned short* __restrict__ rootPrev,
    const unsigned char* __restrict__ hWp,
    const int* __restrict__ rs, const int* __restrict__ ren,
    const unsigned short* __restrict__ ssrc,
    const int* __restrict__ batch,
    float* __restrict__ pooled) {
  __shared__ float h3s[16 * 64];              // 4KB
  __shared__ int batch_s[16];
  const int t = threadIdx.x;
  const int n0 = blockIdx.x * 16;
  if (t < 16) batch_s[t] = batch[n0 + t];

  const int r = t >> 4, l16 = t & 15, c4 = l16 * 4;
  const int node = n0 + r;
  float4 a0 = gather_node(rootPrev, hWp, ssrc, node, c4, rs[node], ren[node]);
  float4 o;
  o.x = fmaxf(a0.x, 0.f); o.y = fmaxf(a0.y, 0.f);
  o.z = fmaxf(a0.z, 0.f); o.w = fmaxf(a0.w, 0.f);
  *(float4*)&h3s[r * 64 + c4] = o;
  __syncthreads();

  if (t < 64) {                               // run-accumulate by graph, then atomics
    int cur = batch_s[0]; float acc = 0.f;
    #pragma unroll
    for (int rr = 0; rr < 16; ++rr) {
      int g = batch_s[rr];
      if (g != cur) {
        unsafeAtomicAdd(&pooled[cur * 64 + t], acc);
        acc = 0.f; cur = g;
      }
      acc += h3s[rr * 64 + t];
    }
    unsafeAtomicAdd(&pooled[cur * 64 + t], acc);
  }
}

// ------- MLP head: one 64-thread block per graph -------
__global__ __launch_bounds__(64) void head_kernel(
    const float* __restrict__ pooled, const int* __restrict__ gstart,
    const float* __restrict__ Wfc1, const float* __restrict__ bfc1,
    const float* __restrict__ Wfc2, const float* __restrict__ bfc2,
    float* __restrict__ out) {
  __shared__ float m[64];
  __shared__ float h1[32];
  const int g = blockIdx.x, l = threadIdx.x;
  float c = fmaxf((float)(gstart[g + 1] - gstart[g]), 1.0f);
  m[l] = pooled[g * 64 + l] / c;
  __syncthreads();
  if (l < 32) {
    float a = bfc1[l];
    #pragma unroll
    for (int k = 0; k < 64; ++k) a += m[k] * Wfc1[k * 32 + l];
    h1[l] = fmaxf(a, 0.f);
  }
  __syncthreads();
  if (l == 0) {
    float o = bfc2[0];
    #pragma unroll
    for (int j = 0; j < 32; ++j) o += h1[j] * Wfc2[j];
    out[g] = o;
  }
}

extern "C" void kernel_launch(void* const* d_in, const int* in_sizes, int n_in,
                              void* d_out, int out_size, void* d_ws, size_t ws_size,
                              hipStream_t stream) {
  const float* x      = (const float*)d_in[0];
  const int*   ei     = (const int*)d_in[1];
  const int*   batch  = (const int*)d_in[2];
  const float* Wrel1  = (const float*)d_in[3];
  const float* brel1  = (const float*)d_in[4];
  const float* Wroot1 = (const float*)d_in[5];
  const float* Wrel2  = (const float*)d_in[6];
  const float* brel2  = (const float*)d_in[7];
  const float* Wroot2 = (const float*)d_in[8];
  const float* Wrel3  = (const float*)d_in[9];
  const float* brel3  = (const float*)d_in[10];
  const float* Wroot3 = (const float*)d_in[11];
  const float* Wfc1   = (const float*)d_in[12];
  const float* bfc1   = (const float*)d_in[13];
  const float* Wfc2   = (const float*)d_in[14];
  const float* bfc2   = (const float*)d_in[15];
  const int* src = ei;
  const int* dst = ei + NE;

  char* w = (char*)d_ws;
  auto alloc = [&](size_t bytes) -> char* {
    char* p = w; w += (bytes + 255) & ~(size_t)255; return p;
  };
  unsigned char*  hWa   = (unsigned char*)alloc((size_t)NN * 64);       // fp8
  unsigned char*  hWb   = (unsigned char*)alloc((size_t)NN * 64);       // fp8
  unsigned short* rootA = (unsigned short*)alloc((size_t)NN * 64 * 2);  // bf16
  unsigned short* rootB = (unsigned short*)alloc((size_t)NN * 64 * 2);  // bf16
  int*   rs     = (int*)alloc((size_t)NBK * 64 * 4);
  int*   ren    = (int*)alloc((size_t)NBK * 64 * 4);
  unsigned short* ssrc = (unsigned short*)alloc((size_t)NBK * CAP * 2);
  int*   gstart = (int*)alloc((size_t)(GRAPHS + 1) * 4);
  int*   bcnt   = (int*)alloc((size_t)NBK * 4);
  float* pooled = (float*)alloc((size_t)GRAPHS * 64 * 4);
  unsigned* ebuf = (unsigned*)alloc((size_t)NBK * CAP * 4);
  unsigned short* Wt1 = (unsigned short*)alloc((size_t)128 * 128 * 2);
  unsigned short* Wt2 = (unsigned short*)alloc((size_t)128 * 64 * 2);
  unsigned short* Wt3 = (unsigned short*)alloc((size_t)128 * 64 * 2);

  setup_kernel<<<64, 256, 0, stream>>>(batch, gstart, bcnt, pooled,
                                       Wrel1, Wroot1, Wrel2, Wroot2, Wrel3, Wroot3,
                                       Wt1, Wt2, Wt3);
  // merged: gemm_l1 (blocks 0..781) + bin (blocks 782..977)
  bin_gemm1_kernel<<<GG1 + (NE + 4095) / 4096, 256, 0, stream>>>(
      x, Wt1, brel1, hWa, rootA, src, dst, bcnt, ebuf);
  bucket_csr_kernel<<<NBK, 256, 0, stream>>>(ebuf, bcnt, rs, ren, ssrc);

  // layer 2: a2 = relu(rootA + G(hWa)); hWb = a2@Wrel2, rootB = a2@Wroot2 + b2
  agg_gemm_kernel<<<NN / 16, 256, 0, stream>>>(rootA, hWa, rs, ren, ssrc,
                                               Wt2, brel2, hWb, rootB);
  // layer 3: a3 = relu(rootB + G(hWb)); hWa = a3@Wrel3, rootA = a3@Wroot3 + b3
  agg_gemm_kernel<<<NN / 16, 256, 0, stream>>>(rootB, hWb, rs, ren, ssrc,
                                               Wt3, brel3, hWa, rootA);
  // h3 = relu(rootA + G(hWa)) -> pooled (atomics); h3 never hits memory
  agg_pool_kernel<<<NN / 16, 256, 0, stream>>>(rootA, hWa, rs, ren, ssrc,
                                               batch, pooled);
  head_kernel<<<GRAPHS, 64, 0, stream>>>(pooled, gstart, Wfc1, bfc1, Wfc2, bfc2,
                                         (float*)d_out);
}